// Round 19
// baseline (26.490 us; speedup 1.0000x reference)
//
#include <hip/hip_runtime.h>
#include <hip/hip_bf16.h>
#include <math.h>

#define KC 32
#define DC 128
#define QC 16
#define NPTS 20000

// ws layout (bytes):
//   c2p[32] f32        @ 0
//   btG[544*128] bf16  @ 128     (PRE-SWIZZLED: elem (gr,col) at seg^(gr&15))
#define WS_C2P_B 0
#define WS_BTG_B 128

typedef __attribute__((ext_vector_type(8))) short bf16x8;
typedef __attribute__((ext_vector_type(4))) float f32x4;

// round-to-nearest-even bf16
static __device__ __forceinline__ short f2bf(float x) {
    union { float f; unsigned u; } v; v.f = x;
    unsigned r = v.u + 0x7fffu + ((v.u >> 16) & 1u);
    return (short)(r >> 16);
}

// ---------------------------------------------------------------------------
// Kernel 1: per-component Woodbury precompute ONLY (32 blocks).
// Emits G/sqrt2 + w' rows (bf16, pre-swizzled column layout) and C2'.
// ---------------------------------------------------------------------------
__global__ __launch_bounds__(256) void mfa_pre(
    const float* __restrict__ log_pi, const float* __restrict__ mu,
    const float* __restrict__ Lam, const float* __restrict__ log_psi,
    float* __restrict__ c2p, short* __restrict__ btG)
{
    int k = blockIdx.x, t = threadIdx.x;
    __shared__ float invpsiS[DC], muS[DC];
    __shared__ float lamR[DC*17];
    __shared__ float lamSc[DC*17];
    __shared__ float MS[QC*QC], LSm[QC*QC];
    __shared__ float invDS[QC];
    __shared__ float GT[QC*129];
    __shared__ float hS[QC];
    __shared__ float redS[4];
    __shared__ float hhS, ldS;

    float lp = 0.f, ipm = 0.f;
    if (t < DC) {
        float psi = expf(log_psi[t]) + 1e-5f + 1e-4f;
        float ip = 1.0f / psi;
        invpsiS[t] = ip;
        lp = logf(psi);
        float m = mu[k*DC + t];
        muS[t] = m;
        ipm = ip*m*m;
    }
    __syncthreads();
    for (int e = t; e < DC*QC; e += 256) {
        int d = e >> 4, q = e & 15;
        float lv = Lam[k*DC*QC + e];
        lamR[d*17 + q]  = lv;
        lamSc[d*17 + q] = lv * invpsiS[d];
    }
    __syncthreads();
    {   // M = I + Lam^T diag(invpsi) Lam
        int q = t >> 4, r = t & 15;
        float s0 = (q == r) ? 1.0f : 0.0f, s1 = 0.f, s2 = 0.f, s3 = 0.f;
#pragma unroll 1
        for (int d = 0; d < DC; d += 4) {
            s0 = fmaf(lamSc[(d+0)*17 + q], lamR[(d+0)*17 + r], s0);
            s1 = fmaf(lamSc[(d+1)*17 + q], lamR[(d+1)*17 + r], s1);
            s2 = fmaf(lamSc[(d+2)*17 + q], lamR[(d+2)*17 + r], s2);
            s3 = fmaf(lamSc[(d+3)*17 + q], lamR[(d+3)*17 + r], s3);
        }
        MS[q*QC + r] = (s0 + s1) + (s2 + s3);
    }
    __syncthreads();
    if (t < QC) {       // 16-lane shuffle Cholesky
        float m[QC], lrow[QC];
#pragma unroll
        for (int j = 0; j < QC; j++) m[j] = MS[t*QC + j];
#pragma unroll
        for (int j = 0; j < QC; j++) {
            float piv = __shfl(m[j], j, 16);
            float ljj = sqrtf(piv);
            float lij = m[j] / ljj;
            lrow[j] = lij;
#pragma unroll
            for (int r = j + 1; r < QC; r++)
                m[r] = fmaf(-lij, __shfl(lij, r, 16), m[r]);
        }
#pragma unroll
        for (int j = 0; j < QC; j++) LSm[t*QC + j] = lrow[j];
        invDS[t] = 1.0f / lrow[t];
        float ld = 2.0f * logf(lrow[t]);
        ld += __shfl_xor(ld, 1, 16);
        ld += __shfl_xor(ld, 2, 16);
        ld += __shfl_xor(ld, 4, 16);
        ld += __shfl_xor(ld, 8, 16);
        if (t == 0) ldS = ld;
    }
    __syncthreads();
    float g[QC];
    if (t < DC) {       // forward solve: column t of G
        float b[QC];
#pragma unroll
        for (int q = 0; q < QC; q++) b[q] = lamSc[t*17 + q];
#pragma unroll
        for (int i = 0; i < QC; i++) {
            float s = b[i];
#pragma unroll
            for (int x = 0; x < i; x++)
                s = fmaf(-LSm[i*QC + x], g[x], s);
            g[i] = s * invDS[i];
        }
        const float is2 = 0.70710678118654752f;
        int seg = t >> 3, w8 = t & 7;
#pragma unroll
        for (int q = 0; q < QC; q++) {
            GT[q*129 + t] = g[q];
            // pre-swizzled store: column seg -> seg ^ (gr&15), gr&15 == q
            btG[(k*QC + q)*DC + ((seg ^ q) << 3) + w8] = f2bf(g[q] * is2);
        }
    }
    __syncthreads();
    if (t < QC) {       // h = G mu
        float s = 0.f;
        for (int d = 0; d < DC; d++)
            s = fmaf(GT[t*129 + d], muS[d], s);
        hS[t] = s;
        float hh = s*s;
        hh += __shfl_xor(hh, 1, 16);
        hh += __shfl_xor(hh, 2, 16);
        hh += __shfl_xor(hh, 4, 16);
        hh += __shfl_xor(hh, 8, 16);
        if (t == 0) hhS = hh;
    }
    {
        float a = lp, b2 = ipm;
#pragma unroll
        for (int off = 1; off < 64; off <<= 1) {
            a  += __shfl_xor(a, off, 64);
            b2 += __shfl_xor(b2, off, 64);
        }
        if (t == 0)  { redS[0] = a; redS[1] = b2; }
        if (t == 64) { redS[2] = a; redS[3] = b2; }
    }
    __syncthreads();
    if (t < DC) {       // w' = invpsi*mu - G^T h  (pre-swizzled, key k&15)
        float gh = 0.f;
#pragma unroll
        for (int q = 0; q < QC; q++) gh = fmaf(g[q], hS[q], gh);
        float wp = invpsiS[t]*muS[t] - gh;
        int seg = t >> 3, w8 = t & 7;
        btG[(512 + k)*DC + ((seg ^ (k & 15)) << 3) + w8] = f2bf(wp);
    }
    if (t == 0) {
        const float log2pi = 1.8378770664093453f;
        float slp = redS[0] + redS[2];
        float tv  = redS[1] + redS[3];
        c2p[k] = log_pi[k]
            - 0.5f*((float)DC*log2pi + slp + ldS + tv) + 0.5f*hhS;
    }
}

// ---------------------------------------------------------------------------
// Kernel 2: all-components GEMM + in-register logsumexp, with X conversion
// FUSED (reads X f32 directly; no xH/s2 round-trip). Grid 313, 2 blocks/CU
// (74.2 KB LDS). 4-phase quarter staging (verified r18 schedule). X loads
// issued before the first barrier so HBM latency hides under phase-0 stage.
// ---------------------------------------------------------------------------
#define QBUF 36864   // 9 tiles * 4096 B

#define STG(START, NT, BUF) do {                                              \
    _Pragma("unroll")                                                         \
    for (int i = 0; i < (NT); i++) {                                          \
        int c = t + i*256;                                                    \
        int within = c & 255;                                                 \
        int r16_ = within >> 4, seg = within & 15;                            \
        int tt = (START) + (c >> 8);                                          \
        int gr = (tt < 32) ? (tt*16 + r16_) : (512 + (tt - 32)*16 + r16_);    \
        const short* gsrc = btG + (size_t)gr*DC + seg*8;                      \
        __builtin_amdgcn_global_load_lds(                                     \
            (const __attribute__((address_space(1))) unsigned int*)gsrc,      \
            (__attribute__((address_space(3))) unsigned int*)                 \
                ((BUF) + (size_t)c*16),                                       \
            16, 0, 0);                                                        \
    }                                                                         \
} while (0)

#define CG(SLOT0, CNT, BUF, QARR, QOFF) do {                                  \
    _Pragma("unroll")                                                         \
    for (int s = 0; s < (CNT); s++) {                                         \
        f32x4 acc = (f32x4){0.f, 0.f, 0.f, 0.f};                              \
        unsigned base = (unsigned)((((SLOT0) + s)*4096) + m16*256);           \
        _Pragma("unroll")                                                     \
        for (int ks = 0; ks < 4; ks++) {                                      \
            unsigned bo = base + ((((unsigned)(ks*4 + g4)) ^ (unsigned)m16) << 4); \
            bf16x8 bh = *(const bf16x8*)((BUF) + bo);                         \
            acc = __builtin_amdgcn_mfma_f32_16x16x32_bf16(bh, aH[ks], acc, 0, 0, 0); \
        }                                                                     \
        float sq = acc[0]*acc[0];                                             \
        sq = fmaf(acc[1], acc[1], sq);                                        \
        sq = fmaf(acc[2], acc[2], sq);                                        \
        sq = fmaf(acc[3], acc[3], sq);                                        \
        sq += __shfl_xor(sq, 16, 64);                                         \
        sq += __shfl_xor(sq, 32, 64);                                         \
        (QARR)[(QOFF) + s] = sq;                                              \
    }                                                                         \
} while (0)

#define CW(SLOT, BUF, ACCW) do {                                              \
    unsigned base = (unsigned)(((SLOT)*4096) + m16*256);                      \
    _Pragma("unroll")                                                         \
    for (int ks = 0; ks < 4; ks++) {                                          \
        unsigned bo = base + ((((unsigned)(ks*4 + g4)) ^ (unsigned)m16) << 4);\
        bf16x8 bh = *(const bf16x8*)((BUF) + bo);                             \
        ACCW = __builtin_amdgcn_mfma_f32_16x16x32_bf16(bh, aH[ks], ACCW, 0, 0, 0); \
    }                                                                         \
} while (0)

__global__ __launch_bounds__(256, 2) void mfa_gemm(
    const float* __restrict__ X, const float* __restrict__ log_psi,
    const float* __restrict__ c2p, const short* __restrict__ btG,
    float* __restrict__ out)
{
    __shared__ __align__(16) char ldsB[2*QBUF];      // 73728 B
    __shared__ float invpsiS[DC];                    // +512 B
    char* buf0 = ldsB;
    char* buf1 = ldsB + QBUF;
    int t = threadIdx.x;
    int w = t >> 6, l = t & 63;
    int m16 = l & 15, g4 = l >> 4;
    int xb = blockIdx.x;                             // 0..312
    int rb0 = xb*64 + w*16;

    // ---- issue X row loads (f32) early; hide under phase-0 staging ----
    int tile16 = min(xb*4 + w, (NPTS >> 4) - 1);
    const float* xrow = X + (size_t)(tile16*16 + m16)*DC;
    float4 xv[8];
#pragma unroll
    for (int ks = 0; ks < 4; ks++) {
        xv[2*ks]   = *(const float4*)(xrow + ks*32 + g4*8);
        xv[2*ks+1] = *(const float4*)(xrow + ks*32 + g4*8 + 4);
    }
    // invpsi into LDS (ready after the first barrier)
    if (t < DC) invpsiS[t] = 1.0f / (expf(log_psi[t]) + 1e-5f + 1e-4f);

    STG(0, 9, buf0);
    __syncthreads();                       // buf0 p0 + invpsiS ready

    // ---- convert to bf16 fragments + s2 (in-register) ----
    bf16x8 aH[4];
    float s2p = 0.f;
#pragma unroll
    for (int ks = 0; ks < 4; ks++) {
        float xs[8], is[8];
        *(float4*)&xs[0] = xv[2*ks];
        *(float4*)&xs[4] = xv[2*ks+1];
        const float* ip = invpsiS + ks*32 + g4*8;
        *(float4*)&is[0] = *(const float4*)(ip);
        *(float4*)&is[4] = *(const float4*)(ip + 4);
#pragma unroll
        for (int j = 0; j < 8; j++) {
            aH[ks][j] = f2bf(xs[j]);
            s2p = fmaf(xs[j]*is[j], xs[j], s2p);
        }
    }
    s2p *= 0.5f;
    s2p += __shfl_xor(s2p, 16, 64);
    s2p += __shfl_xor(s2p, 32, 64);

    float quadA[16], quadB[16];
    f32x4 accwA = (f32x4){0.f, 0.f, 0.f, 0.f};
    f32x4 accwB = (f32x4){0.f, 0.f, 0.f, 0.f};

    // ---- 4-phase pipeline: stage(p+1) issued before compute(p) ----
    STG(9, 9, buf1);                       // hides under p0 compute
    CG(0, 9, buf0, quadA, 0);              // tiles 0-8  -> comps 0-8
    __syncthreads();                       // buf1 p1 ready
    STG(18, 8, buf0);                      // hides under p1 compute
    CG(0, 7, buf1, quadA, 9);              // tiles 9-15 -> comps 9-15
    CG(7, 2, buf1, quadB, 0);              // tiles 16-17 -> comps 16-17
    __syncthreads();                       // buf0 p2 ready
    STG(26, 8, buf1);                      // hides under p2 compute
    CG(0, 8, buf0, quadB, 2);              // tiles 18-25 -> comps 18-25
    __syncthreads();                       // buf1 p3 ready
    CG(0, 6, buf1, quadB, 10);             // tiles 26-31 -> comps 26-31
    CW(6, buf1, accwA);                    // tile 32: w' comps 0-15
    CW(7, buf1, accwB);                    // tile 33: w' comps 16-31

    // ---- assemble lr and in-register logsumexp ----
    float lrA[4], lrB[4];
    float4 c2vA = *(const float4*)(c2p + g4*4);
    float4 c2vB = *(const float4*)(c2p + 16 + g4*4);
#pragma unroll
    for (int j = 0; j < 4; j++) {
        float qvA = (g4 == 0) ? quadA[j] : (g4 == 1) ? quadA[4+j]
                  : (g4 == 2) ? quadA[8+j] : quadA[12+j];
        float qvB = (g4 == 0) ? quadB[j] : (g4 == 1) ? quadB[4+j]
                  : (g4 == 2) ? quadB[8+j] : quadB[12+j];
        float c2jA = (j == 0) ? c2vA.x : (j == 1) ? c2vA.y
                   : (j == 2) ? c2vA.z : c2vA.w;
        float c2jB = (j == 0) ? c2vB.x : (j == 1) ? c2vB.y
                   : (j == 2) ? c2vB.z : c2vB.w;
        lrA[j] = c2jA + accwA[j] - s2p + qvA;
        lrB[j] = c2jB + accwB[j] - s2p + qvB;
    }

    float mx = fmaxf(fmaxf(fmaxf(lrA[0], lrA[1]), fmaxf(lrA[2], lrA[3])),
                     fmaxf(fmaxf(lrB[0], lrB[1]), fmaxf(lrB[2], lrB[3])));
    mx = fmaxf(mx, __shfl_xor(mx, 16, 64));
    mx = fmaxf(mx, __shfl_xor(mx, 32, 64));
    float s = 0.f;
#pragma unroll
    for (int j = 0; j < 4; j++) s += expf(lrA[j] - mx);
#pragma unroll
    for (int j = 0; j < 4; j++) s += expf(lrB[j] - mx);
    s += __shfl_xor(s, 16, 64);
    s += __shfl_xor(s, 32, 64);
    float ll = mx + logf(s);

    int grow = rb0 + m16;
    if (grow < NPTS) {
        float4 o0, o1;
        o0.x = lrA[0] - ll; o0.y = lrA[1] - ll;
        o0.z = lrA[2] - ll; o0.w = lrA[3] - ll;
        o1.x = lrB[0] - ll; o1.y = lrB[1] - ll;
        o1.z = lrB[2] - ll; o1.w = lrB[3] - ll;
        float* op = out + (size_t)grow*KC;
        *(float4*)(op + g4*4)      = o0;
        *(float4*)(op + 16 + g4*4) = o1;
        if (g4 == 0) out[(size_t)NPTS*KC + grow] = ll;
    }
}

extern "C" void kernel_launch(void* const* d_in, const int* in_sizes, int n_in,
                              void* d_out, int out_size, void* d_ws, size_t ws_size,
                              hipStream_t stream)
{
    const float* X       = (const float*)d_in[0];
    const float* log_pi  = (const float*)d_in[1];
    const float* mu      = (const float*)d_in[2];
    const float* Lam     = (const float*)d_in[3];
    const float* log_psi = (const float*)d_in[4];
    float* out = (float*)d_out;
    char* wsb = (char*)d_ws;
    float* c2p = (float*)(wsb + WS_C2P_B);
    short* btG = (short*)(wsb + WS_BTG_B);

    hipLaunchKernelGGL(mfa_pre, dim3(KC), dim3(256), 0, stream,
                       log_pi, mu, Lam, log_psi, c2p, btG);
    hipLaunchKernelGGL(mfa_gemm, dim3(313), dim3(256), 0, stream,
                       X, log_psi, c2p, btG, out);
}

// Round 20
// 24.763 us; speedup vs baseline: 1.0697x; 1.0697x over previous
//
#include <hip/hip_runtime.h>
#include <hip/hip_bf16.h>
#include <math.h>

#define KC 32
#define DC 128
#define QC 16
#define NPTS 20000

// ws layout (bytes):
//   c2p[32] f32        @ 0
//   btG[544*128] bf16  @ 128     (PRE-SWIZZLED: elem (gr,col) at seg^(gr&15))
//   s2h[20000] f32     @ 139392  (0.5 * x^T invpsi x)
//   XH[1250*2048] s    @ 219520  (fragment-major bf16 X)
#define WS_C2P_B 0
#define WS_BTG_B 128
#define WS_S2_B  139392
#define WS_XH_B  219520

typedef __attribute__((ext_vector_type(8))) short bf16x8;
typedef __attribute__((ext_vector_type(4))) float f32x4;

// round-to-nearest-even bf16
static __device__ __forceinline__ short f2bf(float x) {
    union { float f; unsigned u; } v; v.f = x;
    unsigned r = v.u + 0x7fffu + ((v.u >> 16) & 1u);
    return (short)(r >> 16);
}

// ---------------------------------------------------------------------------
// Kernel 1 (fused prep): blocks 0..31 per-component Woodbury precompute
// (G/sqrt2 + w' rows, bf16, PRE-SWIZZLED column layout; C2'); blocks 32+
// convert 64 X rows each to bf16 fragment-major and store 0.5*x^T invpsi x.
// ---------------------------------------------------------------------------
__global__ __launch_bounds__(256) void mfa_prep(
    const float* __restrict__ X, const float* __restrict__ log_pi,
    const float* __restrict__ mu, const float* __restrict__ Lam,
    const float* __restrict__ log_psi,
    float* __restrict__ c2p, short* __restrict__ btG,
    short* __restrict__ xH, float* __restrict__ s2g)
{
    int t = threadIdx.x;
    if (blockIdx.x >= KC) {
        // ---- conversion path ----
        int xb = blockIdx.x - KC;          // 0..312
        int cseg = t & 15, rloc = t >> 4;
        int c0 = cseg * 8;
        float is[8];
#pragma unroll
        for (int j = 0; j < 8; j++) {
            float psi = expf(log_psi[c0 + j]) + 1e-5f + 1e-4f;
            is[j] = 1.0f / psi;
        }
#pragma unroll
        for (int p = 0; p < 4; p++) {
            int r = xb*64 + p*16 + rloc;
            if (r < NPTS) {
                float xs[8];
                const float* xp = X + (size_t)r*DC + c0;
                *(float4*)&xs[0] = *(const float4*)xp;
                *(float4*)&xs[4] = *(const float4*)(xp + 4);
                bf16x8 hv;
                float s2 = 0.f;
#pragma unroll
                for (int j = 0; j < 8; j++) {
                    hv[j] = f2bf(xs[j]);
                    s2 = fmaf(xs[j]*is[j], xs[j], s2);
                }
                size_t fa = (size_t)(r >> 4)*2048 + (size_t)(cseg >> 2)*512
                          + (size_t)(cseg & 3)*128 + (size_t)(r & 15)*8;
                *(bf16x8*)(xH + fa) = hv;
                s2 += __shfl_xor(s2, 1, 16);
                s2 += __shfl_xor(s2, 2, 16);
                s2 += __shfl_xor(s2, 4, 16);
                s2 += __shfl_xor(s2, 8, 16);
                if (cseg == 0) s2g[r] = 0.5f * s2;
            }
        }
        return;
    }
    // ---- per-component Woodbury path ----
    int k = blockIdx.x;
    __shared__ float invpsiS[DC], muS[DC];
    __shared__ float lamR[DC*17];
    __shared__ float lamSc[DC*17];
    __shared__ float MS[QC*QC], LSm[QC*QC];
    __shared__ float invDS[QC];
    __shared__ float GT[QC*129];
    __shared__ float hS[QC];
    __shared__ float redS[4];
    __shared__ float hhS, ldS;

    float lp = 0.f, ipm = 0.f;
    if (t < DC) {
        float psi = expf(log_psi[t]) + 1e-5f + 1e-4f;
        float ip = 1.0f / psi;
        invpsiS[t] = ip;
        lp = logf(psi);
        float m = mu[k*DC + t];
        muS[t] = m;
        ipm = ip*m*m;
    }
    __syncthreads();
    for (int e = t; e < DC*QC; e += 256) {
        int d = e >> 4, q = e & 15;
        float lv = Lam[k*DC*QC + e];
        lamR[d*17 + q]  = lv;
        lamSc[d*17 + q] = lv * invpsiS[d];
    }
    __syncthreads();
    {   // M = I + Lam^T diag(invpsi) Lam
        int q = t >> 4, r = t & 15;
        float s0 = (q == r) ? 1.0f : 0.0f, s1 = 0.f, s2 = 0.f, s3 = 0.f;
#pragma unroll 1
        for (int d = 0; d < DC; d += 4) {
            s0 = fmaf(lamSc[(d+0)*17 + q], lamR[(d+0)*17 + r], s0);
            s1 = fmaf(lamSc[(d+1)*17 + q], lamR[(d+1)*17 + r], s1);
            s2 = fmaf(lamSc[(d+2)*17 + q], lamR[(d+2)*17 + r], s2);
            s3 = fmaf(lamSc[(d+3)*17 + q], lamR[(d+3)*17 + r], s3);
        }
        MS[q*QC + r] = (s0 + s1) + (s2 + s3);
    }
    __syncthreads();
    if (t < QC) {       // 16-lane shuffle Cholesky
        float m[QC], lrow[QC];
#pragma unroll
        for (int j = 0; j < QC; j++) m[j] = MS[t*QC + j];
#pragma unroll
        for (int j = 0; j < QC; j++) {
            float piv = __shfl(m[j], j, 16);
            float ljj = sqrtf(piv);
            float lij = m[j] / ljj;
            lrow[j] = lij;
#pragma unroll
            for (int r = j + 1; r < QC; r++)
                m[r] = fmaf(-lij, __shfl(lij, r, 16), m[r]);
        }
#pragma unroll
        for (int j = 0; j < QC; j++) LSm[t*QC + j] = lrow[j];
        invDS[t] = 1.0f / lrow[t];
        float ld = 2.0f * logf(lrow[t]);
        ld += __shfl_xor(ld, 1, 16);
        ld += __shfl_xor(ld, 2, 16);
        ld += __shfl_xor(ld, 4, 16);
        ld += __shfl_xor(ld, 8, 16);
        if (t == 0) ldS = ld;
    }
    __syncthreads();
    float g[QC];
    if (t < DC) {       // forward solve: column t of G
        float b[QC];
#pragma unroll
        for (int q = 0; q < QC; q++) b[q] = lamSc[t*17 + q];
#pragma unroll
        for (int i = 0; i < QC; i++) {
            float s = b[i];
#pragma unroll
            for (int x = 0; x < i; x++)
                s = fmaf(-LSm[i*QC + x], g[x], s);
            g[i] = s * invDS[i];
        }
        const float is2 = 0.70710678118654752f;
        int seg = t >> 3, w8 = t & 7;
#pragma unroll
        for (int q = 0; q < QC; q++) {
            GT[q*129 + t] = g[q];
            // pre-swizzled store: column seg -> seg ^ (gr&15), gr&15 == q
            btG[(k*QC + q)*DC + ((seg ^ q) << 3) + w8] = f2bf(g[q] * is2);
        }
    }
    __syncthreads();
    if (t < QC) {       // h = G mu
        float s = 0.f;
        for (int d = 0; d < DC; d++)
            s = fmaf(GT[t*129 + d], muS[d], s);
        hS[t] = s;
        float hh = s*s;
        hh += __shfl_xor(hh, 1, 16);
        hh += __shfl_xor(hh, 2, 16);
        hh += __shfl_xor(hh, 4, 16);
        hh += __shfl_xor(hh, 8, 16);
        if (t == 0) hhS = hh;
    }
    {
        float a = lp, b2 = ipm;
#pragma unroll
        for (int off = 1; off < 64; off <<= 1) {
            a  += __shfl_xor(a, off, 64);
            b2 += __shfl_xor(b2, off, 64);
        }
        if (t == 0)  { redS[0] = a; redS[1] = b2; }
        if (t == 64) { redS[2] = a; redS[3] = b2; }
    }
    __syncthreads();
    if (t < DC) {       // w' = invpsi*mu - G^T h  (pre-swizzled, key k&15)
        float gh = 0.f;
#pragma unroll
        for (int q = 0; q < QC; q++) gh = fmaf(g[q], hS[q], gh);
        float wp = invpsiS[t]*muS[t] - gh;
        int seg = t >> 3, w8 = t & 7;
        btG[(512 + k)*DC + ((seg ^ (k & 15)) << 3) + w8] = f2bf(wp);
    }
    if (t == 0) {
        const float log2pi = 1.8378770664093453f;
        float slp = redS[0] + redS[2];
        float tv  = redS[1] + redS[3];
        c2p[k] = log_pi[k]
            - 0.5f*((float)DC*log2pi + slp + ldS + tv) + 0.5f*hhS;
    }
}

// ---------------------------------------------------------------------------
// Kernel 2: all-components MFMA GEMM + in-register logsumexp. Grid 313.
// SWAPPED operands: mfma(G_tile, X_frag) -> acc(row=q, col=n). The q-sum is
// 3 in-lane FMAs + 2 shuffles per component. B staged in two 272-row halves
// via global_load_lds (pre-swizzled global, linear dest, XOR on read).
// lr kept in regs; LSE via shuffles; coalesced stores. (verified r15 = 24.78us)
// ---------------------------------------------------------------------------
#define HALF_PASS(HH, LRA) do {                                               \
    _Pragma("unroll")                                                         \
    for (int i = 0; i < 17; i++) {                                            \
        int c = w*1088 + i*64 + l;                                            \
        int row = c >> 4, seg = c & 15;                                       \
        int gr = (row < 256) ? ((HH)*256 + row) : (512 + (HH)*16 + (row-256));\
        const short* gsrc = btG + (size_t)gr*DC + seg*8;                      \
        __builtin_amdgcn_global_load_lds(                                     \
            (const __attribute__((address_space(1))) unsigned int*)gsrc,      \
            (__attribute__((address_space(3))) unsigned int*)                 \
                (ldsB + (size_t)(w*1088 + i*64)*16),                          \
            16, 0, 0);                                                        \
    }                                                                         \
    __syncthreads();                                                          \
    float quad[16];                                                           \
    _Pragma("unroll")                                                         \
    for (int nt = 0; nt < 16; nt++) {                                         \
        f32x4 acc = (f32x4){0.f, 0.f, 0.f, 0.f};                              \
        unsigned brow = (unsigned)(nt*16 + m16);                              \
        unsigned rbse = brow << 8, sw = brow & 15u;                           \
        _Pragma("unroll")                                                     \
        for (int ks = 0; ks < 4; ks++) {                                      \
            unsigned bo = rbse + ((((unsigned)(ks*4 + g4)) ^ sw) << 4);       \
            bf16x8 bh = *(const bf16x8*)(ldsB + bo);                          \
            acc = __builtin_amdgcn_mfma_f32_16x16x32_bf16(bh, aH[ks], acc, 0, 0, 0); \
        }                                                                     \
        float sq = acc[0]*acc[0];                                             \
        sq = fmaf(acc[1], acc[1], sq);                                        \
        sq = fmaf(acc[2], acc[2], sq);                                        \
        sq = fmaf(acc[3], acc[3], sq);                                        \
        sq += __shfl_xor(sq, 16, 64);                                         \
        sq += __shfl_xor(sq, 32, 64);                                         \
        quad[nt] = sq;                                                        \
    }                                                                         \
    f32x4 accw = (f32x4){0.f, 0.f, 0.f, 0.f};                                 \
    {                                                                         \
        unsigned brow = (unsigned)(256 + m16);                                \
        unsigned rbse = brow << 8, sw = brow & 15u;                           \
        _Pragma("unroll")                                                     \
        for (int ks = 0; ks < 4; ks++) {                                      \
            unsigned bo = rbse + ((((unsigned)(ks*4 + g4)) ^ sw) << 4);       \
            bf16x8 bh = *(const bf16x8*)(ldsB + bo);                          \
            accw = __builtin_amdgcn_mfma_f32_16x16x32_bf16(bh, aH[ks], accw, 0, 0, 0); \
        }                                                                     \
    }                                                                         \
    float4 c2v = *(const float4*)(c2p + (HH)*16 + g4*4);                      \
    _Pragma("unroll")                                                         \
    for (int j = 0; j < 4; j++) {                                             \
        float qv = (g4 == 0) ? quad[j] : (g4 == 1) ? quad[4+j]                \
                 : (g4 == 2) ? quad[8+j] : quad[12+j];                        \
        float c2j = (j == 0) ? c2v.x : (j == 1) ? c2v.y                       \
                  : (j == 2) ? c2v.z : c2v.w;                                 \
        LRA[j] = c2j + accw[j] - s2p + qv;                                    \
    }                                                                         \
} while (0)

__global__ __launch_bounds__(256, 2) void mfa_gemm(
    const short* __restrict__ xH, const float* __restrict__ s2g,
    const float* __restrict__ c2p, const short* __restrict__ btG,
    float* __restrict__ out)
{
    __shared__ __align__(16) char ldsB[272*256];     // 69632 B
    int t = threadIdx.x;
    int w = t >> 6, l = t & 63;
    int m16 = l & 15, g4 = l >> 4;
    int xb = blockIdx.x;
    int rb0 = xb*64 + w*16;

    // X fragments (used as the B-operand after the swap; layout symmetric)
    int tile16 = min(xb*4 + w, (NPTS >> 4) - 1);
    const short* ph = xH + (size_t)tile16*2048 + g4*128 + m16*8;
    bf16x8 aH[4];
#pragma unroll
    for (int ks = 0; ks < 4; ks++)
        aH[ks] = *(const bf16x8*)(ph + ks*512);
    float s2p = s2g[min(rb0 + m16, NPTS - 1)];

    float lrA[4], lrB[4];
    HALF_PASS(0, lrA);
    __syncthreads();                 // half-0 reads done before restage
    HALF_PASS(1, lrB);

    // ---- in-register logsumexp over k (8 local + 2 cross-lane steps) ----
    float mx = fmaxf(fmaxf(fmaxf(lrA[0], lrA[1]), fmaxf(lrA[2], lrA[3])),
                     fmaxf(fmaxf(lrB[0], lrB[1]), fmaxf(lrB[2], lrB[3])));
    mx = fmaxf(mx, __shfl_xor(mx, 16, 64));
    mx = fmaxf(mx, __shfl_xor(mx, 32, 64));
    float s = 0.f;
#pragma unroll
    for (int j = 0; j < 4; j++) s += expf(lrA[j] - mx);
#pragma unroll
    for (int j = 0; j < 4; j++) s += expf(lrB[j] - mx);
    s += __shfl_xor(s, 16, 64);
    s += __shfl_xor(s, 32, 64);
    float ll = mx + logf(s);

    int grow = rb0 + m16;
    if (grow < NPTS) {
        float4 o0, o1;
        o0.x = lrA[0] - ll; o0.y = lrA[1] - ll;
        o0.z = lrA[2] - ll; o0.w = lrA[3] - ll;
        o1.x = lrB[0] - ll; o1.y = lrB[1] - ll;
        o1.z = lrB[2] - ll; o1.w = lrB[3] - ll;
        float* op = out + (size_t)grow*KC;
        *(float4*)(op + g4*4)      = o0;
        *(float4*)(op + 16 + g4*4) = o1;
        if (g4 == 0) out[(size_t)NPTS*KC + grow] = ll;
    }
}

extern "C" void kernel_launch(void* const* d_in, const int* in_sizes, int n_in,
                              void* d_out, int out_size, void* d_ws, size_t ws_size,
                              hipStream_t stream)
{
    const float* X       = (const float*)d_in[0];
    const float* log_pi  = (const float*)d_in[1];
    const float* mu      = (const float*)d_in[2];
    const float* Lam     = (const float*)d_in[3];
    const float* log_psi = (const float*)d_in[4];
    float* out = (float*)d_out;
    char* wsb = (char*)d_ws;
    float* c2p = (float*)(wsb + WS_C2P_B);
    short* btG = (short*)(wsb + WS_BTG_B);
    float* s2g = (float*)(wsb + WS_S2_B);
    short* xH  = (short*)(wsb + WS_XH_B);

    hipLaunchKernelGGL(mfa_prep, dim3(KC + 313), dim3(256), 0, stream,
                       X, log_pi, mu, Lam, log_psi, c2p, btG, xH, s2g);
    hipLaunchKernelGGL(mfa_gemm, dim3(313), dim3(256), 0, stream,
                       xH, s2g, c2p, btG, out);
}